// Round 15
// baseline (214.351 us; speedup 1.0000x reference)
//
#include <hip/hip_runtime.h>
#include <hip/hip_bf16.h>
#include <math.h>

#define DEMB 64
#define BM   16    // rows per block (one MFMA M-tile); K split across 2 waves
#define BKF  64    // floats of K per batch (2 MFMA chunks)

using short8 = __attribute__((ext_vector_type(8))) short;
using u16x8  = __attribute__((ext_vector_type(8))) unsigned short;
using f32x4  = __attribute__((ext_vector_type(4))) float;

__device__ __forceinline__ u16x8 cvt_bf8(float4 a0, float4 a1) {
    union { u16x8 s; __hip_bfloat16 h[8]; } u;
    u.h[0] = __float2bfloat16(a0.x);
    u.h[1] = __float2bfloat16(a0.y);
    u.h[2] = __float2bfloat16(a0.z);
    u.h[3] = __float2bfloat16(a0.w);
    u.h[4] = __float2bfloat16(a1.x);
    u.h[5] = __float2bfloat16(a1.y);
    u.h[6] = __float2bfloat16(a1.z);
    u.h[7] = __float2bfloat16(a1.w);
    return u.s;
}

// async global->LDS, 16 B per lane. GLOBAL source is PER-LANE; LDS dest =
// wave-uniform base + lane*16 (automatic).
__device__ __forceinline__ void gl16(const void* gsrc, void* lds) {
    __builtin_amdgcn_global_load_lds(
        (const __attribute__((address_space(1))) unsigned int*)gsrc,
        (__attribute__((address_space(3))) unsigned int*)lds,
        16, 0, 0);
}

// W [Din][64] fp32 -> Wtk k-octet-major bf16: Wtk[(oct*64 + c)*8 + (k&7)],
// K zero-padded (zeros make clamped/junk A in tail harmless).
__global__ __launch_bounds__(256) void prep_wt(
    const float* __restrict__ W, unsigned short* __restrict__ Wtk, int Din)
{
    const int t = blockIdx.x * 256 + threadIdx.x;   // t = oct*64 + c
    const int oct = t >> 6, c = t & 63;
    union { u16x8 v; __hip_bfloat16 h[8]; } u;
    #pragma unroll
    for (int j = 0; j < 8; ++j) {
        int k = oct * 8 + j;
        float x = (k < Din) ? W[(size_t)k * DEMB + c] : 0.f;
        u.h[j] = __float2bfloat16(x);
    }
    *reinterpret_cast<u16x8*>(&Wtk[(size_t)t * 8]) = u.v;
}

// One 16-row tile per block, FULL K; 2 waves split K (even/odd batches).
// Wave-private 3-slot LDS rings, counted per-wave vmcnt, NO in-loop barriers.
// Epilogue: cross-wave reduce + bias + L2-normalize, write normalized emb.
__global__ __launch_bounds__(128) void gemm_emb(
    const float* __restrict__ Xq, const float* __restrict__ Xs,
    const unsigned short* __restrict__ Wtk, const float* __restrict__ bias,
    float* __restrict__ qn, float* __restrict__ sn,
    int Q, int S, int Din, int nQt, int nbatch)
{
    __shared__ float          As[2][3][BM * BKF];   // 2 waves x 3 slots x 4 KB
    __shared__ unsigned short Bs[2][3][8 * 64 * 8]; // 2 waves x 3 slots x 8 KB

    const int tid  = threadIdx.x;
    const int wave = tid >> 6;     // 0..1
    const int lane = tid & 63;

    const bool isS = (int)blockIdx.x >= nQt;
    const float* X = isS ? Xs : Xq;
    const int nrows = isS ? S : Q;
    const int r0 = (isS ? ((int)blockIdx.x - nQt) : (int)blockIdx.x) * BM;
    float* dst = isS ? sn : qn;

    // staging lane coords
    const int g  = lane >> 4;   // row within 4-row group
    const int qp = lane & 15;   // swizzled quad position

    // fragment coords
    const int c16 = lane & 15;
    const int h   = lane >> 4;  // k-group 0..3

    f32x4 acc[4] = { {0.f,0.f,0.f,0.f}, {0.f,0.f,0.f,0.f},
                     {0.f,0.f,0.f,0.f}, {0.f,0.f,0.f,0.f} };

#define STAGE(SL, B) do {                                                      \
    const int kb_ = (B) * BKF;                                                 \
    _Pragma("unroll")                                                          \
    for (int i = 0; i < 4; ++i) {                                              \
        const int rr_ = 4 * i + g;                                             \
        int rg_ = r0 + rr_;                                                    \
        if (rg_ >= nrows) rg_ = nrows - 1;                                     \
        const int q_ = qp ^ rr_;                                               \
        int kq_ = kb_ + 4 * q_;                                                \
        if (kq_ >= Din) kq_ = 0;                                               \
        gl16(X + (size_t)rg_ * Din + kq_,                                      \
             &As[wave][SL][(4 * i) * BKF]);                                    \
    }                                                                          \
    _Pragma("unroll")                                                          \
    for (int j = 0; j < 8; ++j) {                                              \
        gl16(Wtk + ((size_t)((B) * 8 + j) * 64 + lane) * 8,                    \
             &Bs[wave][SL][j * 512]);                                          \
    }                                                                          \
} while (0)

#define COMPUTE(SL, CC) do {                                                   \
    const int qa_ = (CC) * 8 + 2 * h;                                          \
    const float* Ab_ = &As[wave][SL][c16 * BKF];                               \
    float4 fa_ = *reinterpret_cast<const float4*>(Ab_ + ((qa_    ) ^ c16) * 4);\
    float4 fb_ = *reinterpret_cast<const float4*>(Ab_ + ((qa_ + 1) ^ c16) * 4);\
    short8 af_ = (short8)cvt_bf8(fa_, fb_);                                    \
    const int ob_ = ((CC) * 4 + h) * 64;                                       \
    short8 b0_ = *reinterpret_cast<const short8*>(&Bs[wave][SL][(ob_ +  0 + c16) * 8]); \
    short8 b1_ = *reinterpret_cast<const short8*>(&Bs[wave][SL][(ob_ + 16 + c16) * 8]); \
    short8 b2_ = *reinterpret_cast<const short8*>(&Bs[wave][SL][(ob_ + 32 + c16) * 8]); \
    short8 b3_ = *reinterpret_cast<const short8*>(&Bs[wave][SL][(ob_ + 48 + c16) * 8]); \
    acc[0] = __builtin_amdgcn_mfma_f32_16x16x32_bf16(af_, b0_, acc[0], 0, 0, 0);  \
    acc[1] = __builtin_amdgcn_mfma_f32_16x16x32_bf16(af_, b1_, acc[1], 0, 0, 0);  \
    acc[2] = __builtin_amdgcn_mfma_f32_16x16x32_bf16(af_, b2_, acc[2], 0, 0, 0);  \
    acc[3] = __builtin_amdgcn_mfma_f32_16x16x32_bf16(af_, b3_, acc[3], 0, 0, 0);  \
} while (0)

    // this wave owns batches wave, wave+2, wave+4, ... (12 vmem per batch)
    const int bw = wave;
    STAGE(0, bw);
    if (bw + 2 < nbatch) STAGE(1, bw + 2);
    if (bw + 4 < nbatch) STAGE(2, bw + 4);

    int sl = 0;
    for (int bb = bw; bb < nbatch; bb += 2) {
        if (bb + 4 < nbatch)      asm volatile("s_waitcnt vmcnt(24)" ::: "memory");
        else if (bb + 2 < nbatch) asm volatile("s_waitcnt vmcnt(12)" ::: "memory");
        else                      asm volatile("s_waitcnt vmcnt(0)"  ::: "memory");

        COMPUTE(sl, 0);
        COMPUTE(sl, 1);

        // frag ds_reads fully retired before this slot is re-staged (async
        // gl16 writes could otherwise land under the reads)  [rule #18]
        asm volatile("s_waitcnt lgkmcnt(0)" ::: "memory");
        __builtin_amdgcn_sched_barrier(0);

        if (bb + 6 < nbatch) STAGE(sl, bb + 6);
        sl = (sl == 2) ? 0 : sl + 1;
    }

#undef STAGE
#undef COMPUTE

    // cross-wave reduce (wave1 -> LDS, reuse its slot 0), bias, normalize
    __syncthreads();
    float* red = &As[1][0][0];   // 16 x 64 fp32
    if (wave == 1) {
        #pragma unroll
        for (int cb = 0; cb < 4; ++cb)
            #pragma unroll
            for (int i = 0; i < 4; ++i)
                red[(4 * h + i) * 64 + 16 * cb + c16] = acc[cb][i];
    }
    __syncthreads();
    if (wave == 0) {
        float e[4][4], ss[4] = {0.f, 0.f, 0.f, 0.f};
        #pragma unroll
        for (int cb = 0; cb < 4; ++cb) {
            float bv = bias[16 * cb + c16];
            #pragma unroll
            for (int i = 0; i < 4; ++i) {
                e[cb][i] = acc[cb][i] + red[(4 * h + i) * 64 + 16 * cb + c16] + bv;
                ss[i] += e[cb][i] * e[cb][i];
            }
        }
        #pragma unroll
        for (int i = 0; i < 4; ++i) {
            #pragma unroll
            for (int o = 1; o < 16; o <<= 1) ss[i] += __shfl_xor(ss[i], o, 64);
            ss[i] = fmaxf(sqrtf(ss[i]), 1e-8f);
        }
        #pragma unroll
        for (int cb = 0; cb < 4; ++cb)
            #pragma unroll
            for (int i = 0; i < 4; ++i) {
                int row = r0 + 4 * h + i;
                if (row < nrows)
                    dst[(size_t)row * DEMB + 16 * cb + c16] = e[cb][i] / ss[i];
            }
    }
}

// Fused: cosine sims (embeddings pre-normalized), softmax, one-hot bins.
__global__ __launch_bounds__(256) void attend(
    const float* __restrict__ qn_g, const float* __restrict__ sn_g,
    const int* __restrict__ labels, const int* __restrict__ p_nway,
    float* __restrict__ out, int S, int Q)
{
    __shared__ float sn[100][65];
    __shared__ float qn[4][64];
    __shared__ float bins[4][32];
    __shared__ int   lab[100];

    const int tid  = threadIdx.x;
    const int w    = tid >> 6;
    const int lane = tid & 63;
    const int nw   = *p_nway;

    for (int i = tid; i < S * DEMB; i += 256) sn[i >> 6][i & 63] = sn_g[i];
    if (tid < S) lab[tid] = labels[tid];

    const int q = blockIdx.x * 4 + w;
    qn[w][lane] = qn_g[(size_t)q * DEMB + lane];   // already normalized
    if (lane < 32) bins[w][lane] = 0.f;
    __syncthreads();

    const bool v1 = (lane + 64) < S;
    const int  s1 = v1 ? lane + 64 : 0;
    float sim0 = 0.f, sim1 = 0.f;
    #pragma unroll 8
    for (int c = 0; c < DEMB; ++c) {
        float qc = qn[w][c];
        sim0 += qc * sn[lane][c];
        sim1 += qc * sn[s1][c];
    }
    if (!v1) sim1 = -INFINITY;

    float lm = fmaxf(sim0, sim1);
    #pragma unroll
    for (int o = 32; o >= 1; o >>= 1) lm = fmaxf(lm, __shfl_xor(lm, o, 64));
    float e0 = __expf(sim0 - lm);
    float e1 = v1 ? __expf(sim1 - lm) : 0.f;
    float d = e0 + e1;
    #pragma unroll
    for (int o = 32; o >= 1; o >>= 1) d += __shfl_xor(d, o, 64);

    atomicAdd(&bins[w][lab[lane]], e0);
    if (v1) atomicAdd(&bins[w][lab[s1]], e1);
    __syncthreads();

    if (lane < nw) out[(size_t)q * nw + lane] = bins[w][lane] / d;
}

extern "C" void kernel_launch(void* const* d_in, const int* in_sizes, int n_in,
                              void* d_out, int out_size, void* d_ws, size_t ws_size,
                              hipStream_t stream)
{
    const float* sup    = (const float*)d_in[0];
    const int*   labels = (const int*)d_in[1];
    const float* qry    = (const float*)d_in[2];
    const int*   p_nway = (const int*)d_in[3];
    const float* W      = (const float*)d_in[5];
    const float* bias   = (const float*)d_in[6];
    float* out = (float*)d_out;

    const int D   = DEMB;                 // 64
    const int Din = in_sizes[5] / D;      // 21168
    const int Q   = in_sizes[2] / Din;    // 4096
    const int S   = in_sizes[1];          // 100

    const int nbatch = (Din + BKF - 1) / BKF;   // 331
    const int Koct   = nbatch * 8;              // 2648

    // workspace layout: Wtk | qn | sn
    char* wsb = (char*)d_ws;
    size_t wt_bytes = (size_t)Koct * 64 * 16;   // 2.71 MB
    wt_bytes = (wt_bytes + 255) & ~(size_t)255;
    size_t qn_bytes = (size_t)Q * D * sizeof(float);   // 1 MB
    qn_bytes = (qn_bytes + 255) & ~(size_t)255;

    unsigned short* Wtk = (unsigned short*)wsb;
    float* qn = (float*)(wsb + wt_bytes);
    float* sn = (float*)(wsb + wt_bytes + qn_bytes);

    hipLaunchKernelGGL(prep_wt, dim3((Koct * 64) / 256), dim3(256), 0, stream,
                       W, Wtk, Din);

    const int nQt = (Q + BM - 1) / BM;          // 256
    const int nSt = (S + BM - 1) / BM;          // 7
    hipLaunchKernelGGL(gemm_emb, dim3(nQt + nSt), dim3(128), 0, stream,
                       qry, sup, Wtk, bias, qn, sn, Q, S, Din, nQt, nbatch);

    hipLaunchKernelGGL(attend, dim3(Q / 4), dim3(256), 0, stream,
                       qn, sn, labels, p_nway, out, S, Q);
}

// Round 16
// 116.960 us; speedup vs baseline: 1.8327x; 1.8327x over previous
//
#include <hip/hip_runtime.h>
#include <hip/hip_bf16.h>
#include <math.h>

#define DEMB 64
#define BM   64
#define BKF  64    // floats of K per batch (2 MFMA chunks)
#define KSMAX 16   // 66*16=1056 blocks; 72KB LDS -> 2 blocks/CU (proven optimum)

using short8 = __attribute__((ext_vector_type(8))) short;
using u16x8  = __attribute__((ext_vector_type(8))) unsigned short;
using f32x4  = __attribute__((ext_vector_type(4))) float;

__device__ __forceinline__ u16x8 cvt_bf8(float4 a0, float4 a1) {
    union { u16x8 s; __hip_bfloat16 h[8]; } u;
    u.h[0] = __float2bfloat16(a0.x);
    u.h[1] = __float2bfloat16(a0.y);
    u.h[2] = __float2bfloat16(a0.z);
    u.h[3] = __float2bfloat16(a0.w);
    u.h[4] = __float2bfloat16(a1.x);
    u.h[5] = __float2bfloat16(a1.y);
    u.h[6] = __float2bfloat16(a1.z);
    u.h[7] = __float2bfloat16(a1.w);
    return u.s;
}

// async global->LDS, 16 B per lane. GLOBAL source is PER-LANE; LDS dest =
// wave-uniform base + lane*16 (automatic).
__device__ __forceinline__ void gl16(const void* gsrc, void* lds) {
    __builtin_amdgcn_global_load_lds(
        (const __attribute__((address_space(1))) unsigned int*)gsrc,
        (__attribute__((address_space(3))) unsigned int*)lds,
        16, 0, 0);
}

// W [Din][64] fp32 -> Wtk k-octet-major bf16: Wtk[(oct*64 + c)*8 + (k&7)],
// K zero-padded.
__global__ __launch_bounds__(256) void prep_wt(
    const float* __restrict__ W, unsigned short* __restrict__ Wtk, int Din)
{
    const int t = blockIdx.x * 256 + threadIdx.x;   // t = oct*64 + c
    const int oct = t >> 6, c = t & 63;
    union { u16x8 v; __hip_bfloat16 h[8]; } u;
    #pragma unroll
    for (int j = 0; j < 8; ++j) {
        int k = oct * 8 + j;
        float x = (k < Din) ? W[(size_t)k * DEMB + c] : 0.f;
        u.h[j] = __float2bfloat16(x);
    }
    *reinterpret_cast<u16x8*>(&Wtk[(size_t)t * 8]) = u.v;
}

// MFMA GEMM, 3-slot LDS ring + counted vmcnt (loads stay in flight across
// raw s_barrier). Per wave per batch: exactly 6 global_load_lds (4 A + 2 B).
// A: 256-B row segments, XOR-swizzled quads (pre-swizzled source + same XOR
// on read). B: contiguous 1 KB/wave from octet-major Wtk.
__global__ __launch_bounds__(256) void gemm_mfma(
    const float* __restrict__ Xq, const float* __restrict__ Xs,
    const unsigned short* __restrict__ Wtk,
    float* __restrict__ qpart, float* __restrict__ spart,
    int Q, int S, int Din, int nQb, int cpk, int nchunk)
{
    __shared__ float          As[3][BM * BKF];     // 3 x 16 KB
    __shared__ unsigned short Bs[3][8 * 64 * 8];   // 3 x 8 KB

    const int tid  = threadIdx.x;
    const int wave = tid >> 6;
    const int lane = tid & 63;
    const int kg   = blockIdx.y;

    const bool isS = (int)blockIdx.x >= nQb;
    const float* X = isS ? Xs : Xq;
    const int nrows = isS ? S : Q;
    const int r0 = (isS ? ((int)blockIdx.x - nQb) : (int)blockIdx.x) * BM;
    float* part = isS ? spart : qpart;
    const int prow = isS ? 128 : Q;

    // staging lane coords
    const int g  = lane >> 4;   // row within 4-row group
    const int qp = lane & 15;   // swizzled quad position

    // fragment coords
    const int col16 = lane & 15;
    const int frow  = 16 * wave + col16;
    const int fk    = (lane >> 4) * 8;

    f32x4 acc[4] = { {0.f,0.f,0.f,0.f}, {0.f,0.f,0.f,0.f},
                     {0.f,0.f,0.f,0.f}, {0.f,0.f,0.f,0.f} };

    const int b0 = kg * cpk;
    int b1 = b0 + cpk; if (b1 > nchunk) b1 = nchunk;

#define STAGE(SL, B) do {                                                      \
    const int kb_ = (B) * BKF;                                                 \
    _Pragma("unroll")                                                          \
    for (int i = 0; i < 4; ++i) {                                              \
        int rg_ = r0 + 16 * wave + 4 * i + g;                                  \
        if (rg_ >= nrows) rg_ = nrows - 1;                                     \
        const int q_ = qp ^ (4 * i + g);                                       \
        int kq_ = kb_ + 4 * q_;                                                \
        if (kq_ >= Din) kq_ = 0;                                               \
        gl16(X + (size_t)rg_ * Din + kq_,                                      \
             &As[SL][(16 * wave + 4 * i) * BKF]);                              \
    }                                                                          \
    _Pragma("unroll")                                                          \
    for (int j = 0; j < 2; ++j) {                                              \
        gl16(Wtk + ((size_t)((B) * 8 + 2 * wave + j) * 64 + lane) * 8,         \
             &Bs[SL][(2 * wave + j) * 512]);                                   \
    }                                                                          \
} while (0)

#define COMPUTE(SL, CC) do {                                                   \
    const int qa_ = (CC) * 8 + (fk >> 2);                                      \
    const float* Ab_ = &As[SL][frow * BKF];                                    \
    float4 fa_ = *reinterpret_cast<const float4*>(Ab_ + ((qa_    ) ^ col16) * 4); \
    float4 fb_ = *reinterpret_cast<const float4*>(Ab_ + ((qa_ + 1) ^ col16) * 4); \
    u16x8 afu_ = cvt_bf8(fa_, fb_);                                            \
    short8 af_ = (short8)afu_;                                                 \
    const int ob_ = ((CC) * 4 + (fk >> 3)) * 64;                               \
    short8 b0_ = *reinterpret_cast<const short8*>(&Bs[SL][(ob_ +  0 + col16) * 8]); \
    short8 b1_ = *reinterpret_cast<const short8*>(&Bs[SL][(ob_ + 16 + col16) * 8]); \
    short8 b2_ = *reinterpret_cast<const short8*>(&Bs[SL][(ob_ + 32 + col16) * 8]); \
    short8 b3_ = *reinterpret_cast<const short8*>(&Bs[SL][(ob_ + 48 + col16) * 8]); \
    acc[0] = __builtin_amdgcn_mfma_f32_16x16x32_bf16(af_, b0_, acc[0], 0, 0, 0);  \
    acc[1] = __builtin_amdgcn_mfma_f32_16x16x32_bf16(af_, b1_, acc[1], 0, 0, 0);  \
    acc[2] = __builtin_amdgcn_mfma_f32_16x16x32_bf16(af_, b2_, acc[2], 0, 0, 0);  \
    acc[3] = __builtin_amdgcn_mfma_f32_16x16x32_bf16(af_, b3_, acc[3], 0, 0, 0);  \
} while (0)

    // prologue: issue batches b0 and b0+1; do NOT drain.
    STAGE(0, b0);
    if (b0 + 1 < b1) STAGE(1, b0 + 1);

    for (int b = b0; b < b1; ++b) {
        // own-wave loads for batch b complete (6 per batch, in-order retire):
        if (b + 1 < b1) asm volatile("s_waitcnt vmcnt(6)" ::: "memory");
        else            asm volatile("s_waitcnt vmcnt(0)" ::: "memory");
        __builtin_amdgcn_s_barrier();   // all waves' batch-b loads landed

        const int sl = (b - b0) % 3;
        if (b + 2 < b1) STAGE((sl + 2) % 3, b + 2);   // overwrite slot(b-1): safe post-barrier

        COMPUTE(sl, 0);
        COMPUTE(sl, 1);
    }

#undef STAGE
#undef COMPUTE

    // epilogue: C layout col=lane&15, row=(lane>>4)*4+i
    #pragma unroll
    for (int cb = 0; cb < 4; ++cb) {
        #pragma unroll
        for (int i = 0; i < 4; ++i) {
            int row = r0 + 16 * wave + (lane >> 4) * 4 + i;
            if (row < nrows)
                part[((size_t)kg * prow + row) * DEMB + 16 * cb + col16] = acc[cb][i];
        }
    }
}

// Reduce support partials + bias, L2-normalize -> sn [S][64]
__global__ void support_finalize(const float* __restrict__ spart,
                                 const float* __restrict__ bias,
                                 float* __restrict__ sn, int S, int nkg)
{
    int s = blockIdx.x;
    int c = threadIdx.x;  // 64
    float e = bias[c];
    for (int g = 0; g < nkg; ++g)
        e += spart[((size_t)g * 128 + s) * DEMB + c];
    float ss = e * e;
    #pragma unroll
    for (int o = 32; o >= 1; o >>= 1) ss += __shfl_xor(ss, o, 64);
    sn[(size_t)s * DEMB + c] = e / fmaxf(sqrtf(ss), 1e-8f);
}

// Fused: query reduce+bias+normalize, cosine sims, softmax, one-hot bins.
__global__ __launch_bounds__(256) void attend(
    const float* __restrict__ qpart, const float* __restrict__ sn_g,
    const float* __restrict__ bias, const int* __restrict__ labels,
    const int* __restrict__ p_nway, float* __restrict__ out,
    int S, int Q, int nkg)
{
    __shared__ float sn[100][65];
    __shared__ float qn[4][64];
    __shared__ float bins[4][32];
    __shared__ int   lab[100];

    const int tid  = threadIdx.x;
    const int w    = tid >> 6;
    const int lane = tid & 63;
    const int nw   = *p_nway;

    for (int i = tid; i < S * DEMB; i += 256) sn[i >> 6][i & 63] = sn_g[i];
    if (tid < S) lab[tid] = labels[tid];

    const int q = blockIdx.x * 4 + w;

    float e = bias[lane];
    for (int g = 0; g < nkg; ++g)
        e += qpart[((size_t)g * Q + q) * DEMB + lane];
    float ss = e * e;
    #pragma unroll
    for (int o = 32; o >= 1; o >>= 1) ss += __shfl_xor(ss, o, 64);
    e /= fmaxf(sqrtf(ss), 1e-8f);
    qn[w][lane] = e;
    if (lane < 32) bins[w][lane] = 0.f;
    __syncthreads();

    const bool v1 = (lane + 64) < S;
    const int  s1 = v1 ? lane + 64 : 0;
    float sim0 = 0.f, sim1 = 0.f;
    #pragma unroll 8
    for (int c = 0; c < DEMB; ++c) {
        float qc = qn[w][c];
        sim0 += qc * sn[lane][c];
        sim1 += qc * sn[s1][c];
    }
    if (!v1) sim1 = -INFINITY;

    float lm = fmaxf(sim0, sim1);
    #pragma unroll
    for (int o = 32; o >= 1; o >>= 1) lm = fmaxf(lm, __shfl_xor(lm, o, 64));
    float e0 = __expf(sim0 - lm);
    float e1 = v1 ? __expf(sim1 - lm) : 0.f;
    float d = e0 + e1;
    #pragma unroll
    for (int o = 32; o >= 1; o >>= 1) d += __shfl_xor(d, o, 64);

    atomicAdd(&bins[w][lab[lane]], e0);
    if (v1) atomicAdd(&bins[w][lab[s1]], e1);
    __syncthreads();

    if (lane < nw) out[(size_t)q * nw + lane] = bins[w][lane] / d;
}

extern "C" void kernel_launch(void* const* d_in, const int* in_sizes, int n_in,
                              void* d_out, int out_size, void* d_ws, size_t ws_size,
                              hipStream_t stream)
{
    const float* sup    = (const float*)d_in[0];
    const int*   labels = (const int*)d_in[1];
    const float* qry    = (const float*)d_in[2];
    const int*   p_nway = (const int*)d_in[3];
    const float* W      = (const float*)d_in[5];
    const float* bias   = (const float*)d_in[6];
    float* out = (float*)d_out;

    const int D   = DEMB;                 // 64
    const int Din = in_sizes[5] / D;      // 21168
    const int Q   = in_sizes[2] / Din;    // 4096
    const int S   = in_sizes[1];          // 100

    const int nbatch = (Din + BKF - 1) / BKF;   // 331
    const int Koct   = nbatch * 8;              // 2648

    // workspace layout
    char* wsb = (char*)d_ws;
    size_t wt_bytes = (size_t)Koct * 64 * 16;   // 2.71 MB
    wt_bytes = (wt_bytes + 255) & ~(size_t)255;
    size_t sn_bytes = (size_t)S * D * sizeof(float);
    sn_bytes = (sn_bytes + 255) & ~(size_t)255;
    size_t per_ks = ((size_t)Q * D + 128 * D) * sizeof(float);

    size_t fixed = wt_bytes + sn_bytes;
    int ks = 1;
    if (ws_size > fixed + per_ks) {
        size_t avail = (ws_size - fixed) / per_ks;
        ks = (int)(avail < KSMAX ? avail : KSMAX);
        if (ks < 1) ks = 1;
    }
    const int cpk = (nbatch + ks - 1) / ks;       // batches per K-group
    const int nkg = (nbatch + cpk - 1) / cpk;     // actual # groups

    unsigned short* Wtk = (unsigned short*)wsb;
    float* sn    = (float*)(wsb + wt_bytes);
    float* spart = (float*)(wsb + wt_bytes + sn_bytes);
    float* qpart = spart + (size_t)nkg * 128 * D;

    hipLaunchKernelGGL(prep_wt, dim3((Koct * 64) / 256), dim3(256), 0, stream,
                       W, Wtk, Din);

    const int nQb = (Q + BM - 1) / BM;          // 64
    const int nSb = (S + BM - 1) / BM;          // 2
    hipLaunchKernelGGL(gemm_mfma, dim3(nQb + nSb, nkg), dim3(256), 0, stream,
                       qry, sup, Wtk, qpart, spart, Q, S, Din, nQb, cpk, nbatch);

    hipLaunchKernelGGL(support_finalize, dim3(S), dim3(64), 0, stream,
                       spart, bias, sn, S, nkg);

    hipLaunchKernelGGL(attend, dim3(Q / 4), dim3(256), 0, stream,
                       qpart, sn, bias, labels, p_nway, out, S, Q, nkg);
}